// Round 5
// baseline (3712.190 us; speedup 1.0000x reference)
//
#include <hip/hip_runtime.h>

#define TT 512
#define BB 256
#define II 128
#define HH 256

typedef __attribute__((ext_vector_type(8))) short short8;
typedef __attribute__((ext_vector_type(4))) float floatx4;
typedef __attribute__((ext_vector_type(4))) float fvec4;
typedef unsigned long long u64;

// ws layout (shorts): bf16 weights, h1g[2][B][H], h2g[2][B][H], then stamps.
#define OFF_WIH0 0
#define OFF_WHH0 (OFF_WIH0 + 3 * HH * II)
#define OFF_WIH1 (OFF_WHH0 + 3 * HH * HH)
#define OFF_WHH1 (OFF_WIH1 + 3 * HH * HH)
#define W_TOTAL (OFF_WHH1 + 3 * HH * HH)
#define H1G_OFF W_TOTAL
#define H2G_OFF (H1G_OFF + 2 * BB * HH)
#define WS_SHORTS (H2G_OFF + 2 * BB * HH)
#define STAMP_OFF_BYTES (WS_SHORTS * 2)  // 64B-aligned

__device__ __forceinline__ short f2bf(float f) {
  unsigned u = __builtin_bit_cast(unsigned, f);
  u = u + 0x7fffu + ((u >> 16) & 1u);
  return (short)(u >> 16);
}
__device__ __forceinline__ float fast_sigmoid(float x) {
  return __fdividef(1.0f, 1.0f + __expf(-x));
}
__device__ __forceinline__ float fast_tanh(float x) {
  return 1.0f - __fdividef(2.0f, 1.0f + __expf(2.0f * x));
}
__device__ __forceinline__ short8 cvt8(const float* __restrict__ p) {
  fvec4 lo = *(const fvec4*)p;
  fvec4 hi = *(const fvec4*)(p + 4);
  short8 r;
  r[0] = f2bf(lo[0]); r[1] = f2bf(lo[1]); r[2] = f2bf(lo[2]); r[3] = f2bf(lo[3]);
  r[4] = f2bf(hi[0]); r[5] = f2bf(hi[1]); r[6] = f2bf(hi[2]); r[7] = f2bf(hi[3]);
  return r;
}
__device__ __forceinline__ u64 ld64(const u64* p) {
  return __hip_atomic_load(p, __ATOMIC_RELAXED, __HIP_MEMORY_SCOPE_AGENT);
}
__device__ __forceinline__ short8 ld_frag(const u64* rowbase, int qidx) {
  union { u64 q[2]; short8 s; } u;
  u.q[0] = ld64(rowbase + qidx);
  u.q[1] = ld64(rowbase + qidx + 1);
  return u.s;
}

__global__ __launch_bounds__(256) void cvt_weights(
    const float* __restrict__ w0, const float* __restrict__ w1,
    const float* __restrict__ w2, const float* __restrict__ w3,
    short* __restrict__ out) {
  int i = blockIdx.x * 256 + threadIdx.x;
  if (i >= W_TOTAL) return;
  float v;
  if (i < OFF_WHH0)      v = w0[i - OFF_WIH0];
  else if (i < OFF_WIH1) v = w1[i - OFF_WHH0];
  else if (i < OFF_WHH1) v = w2[i - OFF_WIH1];
  else                   v = w3[i - OFF_WHH1];
  out[i] = f2bf(v);
}

__global__ __launch_bounds__(256) void init_state(unsigned* __restrict__ hz,
                                                  unsigned* __restrict__ st) {
  int i = blockIdx.x * 256 + threadIdx.x;
  if (i < 2 * BB * HH) hz[i] = 0u;  // both parities of h1g+h2g
  if (i < 512) st[i] = 0u;          // stamps0[256] + stamps1[256]
}

// 128 blocks = (bt 0..15) x (ht 0..7), 256 thr = 4 waves.
// Wave w: layer = w>>1, sub = w&1 -> owns 16 cols jc = ht*32+sub*16+col, all 3
// gates, weights VGPR-resident. NO barriers / NO LDS in the main loop: per-wave
// stamp slots in L3 (sc1), divergent-lane polling, direct sc1 A-fragment loads.
// Pipeline DAG: L0@t <- {L0@t-1, L1@t-1(buffer backpressure)};
//               L1@t <- {L0@t, L1@t-1}.  Acyclic -> deadlock-free.
__global__ __launch_bounds__(256, 1) void gru_wave(
    const float* __restrict__ x, const short* __restrict__ wb,
    const float* __restrict__ bih0, const float* __restrict__ bhh0,
    const float* __restrict__ bih1, const float* __restrict__ bhh1,
    const float* __restrict__ Wfc, const float* __restrict__ bfc,
    short* __restrict__ h1g, short* __restrict__ h2g,
    unsigned* __restrict__ stamps, float* __restrict__ out) {
  const int tid = threadIdx.x;
  const int lane = tid & 63;
  const int w = tid >> 6;
  const int quad = lane >> 4;
  const int col = lane & 15;
  const int bt = blockIdx.x >> 3;
  const int htb = blockIdx.x & 7;
  const int layer = w >> 1, sub = w & 1;
  const int jc = htb * 32 + sub * 16 + col;  // this lane's output column

  unsigned* s0g = stamps + bt * 16;        // 16 L0-wave slots for this group
  unsigned* s1g = stamps + 256 + bt * 16;  // 16 L1-wave slots
  const int myslot = htb * 2 + sub;
  const int rowq = (bt * 16 + col) * (HH / 4);  // u64 index of this lane's A row
  // poll role: lanes 0..15 watch stamps0, lanes 16..31 watch stamps1
  const unsigned* pslot =
      (lane < 16) ? (s0g + lane) : (s1g + (lane & 15));
  const bool polling = lane < 32;

  float hm[4] = {0.f, 0.f, 0.f, 0.f};  // fp32 master h (rows quad*4+i, col jc)

  if (layer == 0) {
    // ---- weights -> VGPRs: ih K=128 (4 frags/gate), hh K=256 (8 frags/gate)
    short8 wI[3][4], wH[3][8];
#pragma unroll
    for (int g = 0; g < 3; ++g) {
#pragma unroll
      for (int f = 0; f < 4; ++f)
        wI[g][f] = *(const short8*)(wb + OFF_WIH0 + (g * HH + jc) * II + f * 32 + quad * 8);
#pragma unroll
      for (int f = 0; f < 8; ++f)
        wH[g][f] = *(const short8*)(wb + OFF_WHH0 + (g * HH + jc) * HH + f * 32 + quad * 8);
    }
    const float bR = bih0[jc] + bhh0[jc];
    const float bZ = bih0[HH + jc] + bhh0[HH + jc];
    const float bNI = bih0[2 * HH + jc];
    const float bNH = bhh0[2 * HH + jc];

    for (int t = 0; t < TT; ++t) {
      // x[t] fragments (normal cached loads; overlap the poll)
      short8 ax[4];
      const float* xr = x + ((size_t)t * BB + bt * 16 + col) * II + quad * 8;
#pragma unroll
      for (int f = 0; f < 4; ++f) ax[f] = cvt8(xr + f * 32);

      // poll: stamps0 >= t (peers published h1[t-1]); stamps1 >= t-1 (backpressure)
      unsigned tgt = (lane < 16) ? (unsigned)t : (unsigned)(t > 0 ? t - 1 : 0);
      if (polling) {
        int g = 0;
        while (__hip_atomic_load(pslot, __ATOMIC_RELAXED,
                                 __HIP_MEMORY_SCOPE_AGENT) < tgt &&
               g < (1 << 22))
          ++g;
      }

      // h1[t-1] fragments (sc1, L3-coherent)
      const u64* hb = (const u64*)(h1g + ((t + 1) & 1) * BB * HH) + rowq;
      short8 ah[8];
#pragma unroll
      for (int f = 0; f < 8; ++f) ah[f] = ld_frag(hb, f * 8 + quad * 2);

      floatx4 aR = floatx4{bR, bR, bR, bR};
      floatx4 aZ = floatx4{bZ, bZ, bZ, bZ};
      floatx4 aNI = floatx4{bNI, bNI, bNI, bNI};
      floatx4 aNH = floatx4{bNH, bNH, bNH, bNH};
#pragma unroll
      for (int f = 0; f < 4; ++f) {
        aR = __builtin_amdgcn_mfma_f32_16x16x32_bf16(ax[f], wI[0][f], aR, 0, 0, 0);
        aZ = __builtin_amdgcn_mfma_f32_16x16x32_bf16(ax[f], wI[1][f], aZ, 0, 0, 0);
        aNI = __builtin_amdgcn_mfma_f32_16x16x32_bf16(ax[f], wI[2][f], aNI, 0, 0, 0);
      }
#pragma unroll
      for (int f = 0; f < 8; ++f) {
        aR = __builtin_amdgcn_mfma_f32_16x16x32_bf16(ah[f], wH[0][f], aR, 0, 0, 0);
        aZ = __builtin_amdgcn_mfma_f32_16x16x32_bf16(ah[f], wH[1][f], aZ, 0, 0, 0);
        aNH = __builtin_amdgcn_mfma_f32_16x16x32_bf16(ah[f], wH[2][f], aNH, 0, 0, 0);
      }

      // elementwise in-register (rows quad*4+i, col jc) + packed publish
      short* hdst = h1g + (t & 1) * BB * HH;
#pragma unroll
      for (int i = 0; i < 4; ++i) {
        float r = fast_sigmoid(aR[i]);
        float z = fast_sigmoid(aZ[i]);
        float n = fast_tanh(aNI[i] + r * aNH[i]);
        float h = n + z * (hm[i] - n);
        hm[i] = h;
        unsigned hv = (unsigned)(unsigned short)f2bf(h);
        unsigned ov = (unsigned)__builtin_amdgcn_ds_swizzle((int)hv, 0x041F);
        unsigned val = (ov << 16) | hv;  // even lane: (self, partner)
        if (!(lane & 1)) {
          unsigned* dst = (unsigned*)(hdst + (bt * 16 + quad * 4 + i) * HH + (jc & ~1));
          __hip_atomic_store(dst, val, __ATOMIC_RELAXED, __HIP_MEMORY_SCOPE_AGENT);
        }
      }
      __atomic_signal_fence(__ATOMIC_SEQ_CST);
      __builtin_amdgcn_s_waitcnt(0);  // all publishes globally visible (write-through)
      __atomic_signal_fence(__ATOMIC_SEQ_CST);
      if (lane == 0)
        __hip_atomic_store(s0g + myslot, (unsigned)(t + 1), __ATOMIC_RELAXED,
                           __HIP_MEMORY_SCOPE_AGENT);
    }

    // ---- FC epilogue: out tile = h2[511] @ Wfc^T + bfc (L0 waves only) ----
    if (polling && lane >= 16) {
      int g = 0;
      while (__hip_atomic_load(pslot, __ATOMIC_RELAXED,
                               __HIP_MEMORY_SCOPE_AGENT) < (unsigned)TT &&
             g < (1 << 22))
        ++g;
    }
    const u64* hb = (const u64*)(h2g + 1 * BB * HH) + rowq;  // parity 511&1=1
    float bbv = bfc[jc];
    floatx4 acc = floatx4{bbv, bbv, bbv, bbv};
#pragma unroll
    for (int f = 0; f < 8; ++f) {
      short8 a = ld_frag(hb, f * 8 + quad * 2);
      short8 bw = cvt8(Wfc + jc * HH + f * 32 + quad * 8);
      acc = __builtin_amdgcn_mfma_f32_16x16x32_bf16(a, bw, acc, 0, 0, 0);
    }
#pragma unroll
    for (int i = 0; i < 4; ++i)
      out[(size_t)(bt * 16 + quad * 4 + i) * HH + jc] = acc[i];

  } else {
    // ---- layer 1: ih K=256 (8 frags/gate), hh K=256 (8 frags/gate) ----
    short8 wI[3][8], wH[3][8];
#pragma unroll
    for (int g = 0; g < 3; ++g) {
#pragma unroll
      for (int f = 0; f < 8; ++f) {
        wI[g][f] = *(const short8*)(wb + OFF_WIH1 + (g * HH + jc) * HH + f * 32 + quad * 8);
        wH[g][f] = *(const short8*)(wb + OFF_WHH1 + (g * HH + jc) * HH + f * 32 + quad * 8);
      }
    }
    const float bR = bih1[jc] + bhh1[jc];
    const float bZ = bih1[HH + jc] + bhh1[HH + jc];
    const float bNI = bih1[2 * HH + jc];
    const float bNH = bhh1[2 * HH + jc];

    for (int t = 0; t < TT; ++t) {
      // poll: stamps0 >= t+1 (h1[t] ready); stamps1 >= t (h2[t-1] ready)
      unsigned tgt = (lane < 16) ? (unsigned)(t + 1) : (unsigned)t;
      if (polling) {
        int g = 0;
        while (__hip_atomic_load(pslot, __ATOMIC_RELAXED,
                                 __HIP_MEMORY_SCOPE_AGENT) < tgt &&
               g < (1 << 22))
          ++g;
      }

      const u64* h1b = (const u64*)(h1g + (t & 1) * BB * HH) + rowq;        // h1[t]
      const u64* h2b = (const u64*)(h2g + ((t + 1) & 1) * BB * HH) + rowq;  // h2[t-1]
      short8 a1[8], a2[8];
#pragma unroll
      for (int f = 0; f < 8; ++f) a1[f] = ld_frag(h1b, f * 8 + quad * 2);
#pragma unroll
      for (int f = 0; f < 8; ++f) a2[f] = ld_frag(h2b, f * 8 + quad * 2);

      floatx4 aR = floatx4{bR, bR, bR, bR};
      floatx4 aZ = floatx4{bZ, bZ, bZ, bZ};
      floatx4 aNI = floatx4{bNI, bNI, bNI, bNI};
      floatx4 aNH = floatx4{bNH, bNH, bNH, bNH};
#pragma unroll
      for (int f = 0; f < 8; ++f) {
        aR = __builtin_amdgcn_mfma_f32_16x16x32_bf16(a1[f], wI[0][f], aR, 0, 0, 0);
        aZ = __builtin_amdgcn_mfma_f32_16x16x32_bf16(a1[f], wI[1][f], aZ, 0, 0, 0);
        aNI = __builtin_amdgcn_mfma_f32_16x16x32_bf16(a1[f], wI[2][f], aNI, 0, 0, 0);
      }
#pragma unroll
      for (int f = 0; f < 8; ++f) {
        aR = __builtin_amdgcn_mfma_f32_16x16x32_bf16(a2[f], wH[0][f], aR, 0, 0, 0);
        aZ = __builtin_amdgcn_mfma_f32_16x16x32_bf16(a2[f], wH[1][f], aZ, 0, 0, 0);
        aNH = __builtin_amdgcn_mfma_f32_16x16x32_bf16(a2[f], wH[2][f], aNH, 0, 0, 0);
      }

      short* hdst = h2g + (t & 1) * BB * HH;
#pragma unroll
      for (int i = 0; i < 4; ++i) {
        float r = fast_sigmoid(aR[i]);
        float z = fast_sigmoid(aZ[i]);
        float n = fast_tanh(aNI[i] + r * aNH[i]);
        float h = n + z * (hm[i] - n);
        hm[i] = h;
        unsigned hv = (unsigned)(unsigned short)f2bf(h);
        unsigned ov = (unsigned)__builtin_amdgcn_ds_swizzle((int)hv, 0x041F);
        unsigned val = (ov << 16) | hv;
        if (!(lane & 1)) {
          unsigned* dst = (unsigned*)(hdst + (bt * 16 + quad * 4 + i) * HH + (jc & ~1));
          __hip_atomic_store(dst, val, __ATOMIC_RELAXED, __HIP_MEMORY_SCOPE_AGENT);
        }
      }
      __atomic_signal_fence(__ATOMIC_SEQ_CST);
      __builtin_amdgcn_s_waitcnt(0);
      __atomic_signal_fence(__ATOMIC_SEQ_CST);
      if (lane == 0)
        __hip_atomic_store(s1g + myslot, (unsigned)(t + 1), __ATOMIC_RELAXED,
                           __HIP_MEMORY_SCOPE_AGENT);
    }
  }
}

extern "C" void kernel_launch(void* const* d_in, const int* in_sizes, int n_in,
                              void* d_out, int out_size, void* d_ws,
                              size_t ws_size, hipStream_t stream) {
  const float* x = (const float*)d_in[0];
  const float* Wih0 = (const float*)d_in[1];
  const float* Whh0 = (const float*)d_in[2];
  const float* bih0 = (const float*)d_in[3];
  const float* bhh0 = (const float*)d_in[4];
  const float* Wih1 = (const float*)d_in[5];
  const float* Whh1 = (const float*)d_in[6];
  const float* bih1 = (const float*)d_in[7];
  const float* bhh1 = (const float*)d_in[8];
  const float* Wfc = (const float*)d_in[9];
  const float* bfc = (const float*)d_in[10];

  short* wb = (short*)d_ws;
  short* h1g = wb + H1G_OFF;
  short* h2g = wb + H2G_OFF;
  unsigned* stamps = (unsigned*)((char*)d_ws + STAMP_OFF_BYTES);
  unsigned* hz = (unsigned*)(wb + H1G_OFF);

  cvt_weights<<<(W_TOTAL + 255) / 256, 256, 0, stream>>>(Wih0, Whh0, Wih1, Whh1, wb);
  init_state<<<(2 * BB * HH + 255) / 256, 256, 0, stream>>>(hz, stamps);
  gru_wave<<<128, 256, 0, stream>>>(x, wb, bih0, bhh0, bih1, bhh1, Wfc, bfc,
                                    h1g, h2g, stamps, (float*)d_out);
}

// Round 7
// 2239.034 us; speedup vs baseline: 1.6579x; 1.6579x over previous
//
#include <hip/hip_runtime.h>

#define TT 512
#define BB 256
#define II 128
#define HH 256
#define LDW 264  // LDS row stride (shorts): 512B data + 16B pad

typedef __attribute__((ext_vector_type(8))) short short8;
typedef __attribute__((ext_vector_type(4))) float floatx4;
typedef __attribute__((ext_vector_type(4))) float fvec4;
typedef unsigned long long u64;

// ws layout: h1g u32[2][BB][HH/2] | h2g u32[2][BB][HH/2] | wb bf16 | xb bf16 | cnt u32[1024]
#define HBUF_U32 (2 * BB * (HH / 2))
#define OFF_WIH0 0
#define OFF_WHH0 (OFF_WIH0 + 3 * HH * II)
#define OFF_WIH1 (OFF_WHH0 + 3 * HH * HH)
#define OFF_WHH1 (OFF_WIH1 + 3 * HH * HH)
#define W_TOTAL (OFF_WHH1 + 3 * HH * HH)
#define XB_ELEMS ((size_t)TT * BB * II)

__device__ __forceinline__ short f2bf(float f) {
  unsigned u = __builtin_bit_cast(unsigned, f);
  u = u + 0x7fffu + ((u >> 16) & 1u);
  return (short)(u >> 16);
}
__device__ __forceinline__ float fast_sigmoid(float x) {
  return __fdividef(1.0f, 1.0f + __expf(-x));
}
__device__ __forceinline__ float fast_tanh(float x) {
  return 1.0f - __fdividef(2.0f, 1.0f + __expf(2.0f * x));
}
__device__ __forceinline__ short8 cvt8(const float* __restrict__ p) {
  fvec4 lo = *(const fvec4*)p;
  fvec4 hi = *(const fvec4*)(p + 4);
  short8 r;
  r[0] = f2bf(lo[0]); r[1] = f2bf(lo[1]); r[2] = f2bf(lo[2]); r[3] = f2bf(lo[3]);
  r[4] = f2bf(hi[0]); r[5] = f2bf(hi[1]); r[6] = f2bf(hi[2]); r[7] = f2bf(hi[3]);
  return r;
}
__device__ __forceinline__ u64 ld64(const u64* p) {
  return __hip_atomic_load(p, __ATOMIC_RELAXED, __HIP_MEMORY_SCOPE_AGENT);
}
__device__ __forceinline__ void st32(unsigned* p, unsigned v) {
  __hip_atomic_store(p, v, __ATOMIC_RELAXED, __HIP_MEMORY_SCOPE_AGENT);
}
__device__ __forceinline__ void spin_ge(const unsigned* c, unsigned tgt) {
  int g = 0;
  while (__hip_atomic_load(c, __ATOMIC_RELAXED, __HIP_MEMORY_SCOPE_AGENT) < tgt &&
         g < (1 << 22))
    ++g;
}
__device__ __forceinline__ void drain_then(void) {
  __atomic_signal_fence(__ATOMIC_SEQ_CST);
  __builtin_amdgcn_s_waitcnt(0);
  __atomic_signal_fence(__ATOMIC_SEQ_CST);
}

__global__ __launch_bounds__(256) void cvt_weights(
    const float* __restrict__ w0, const float* __restrict__ w1,
    const float* __restrict__ w2, const float* __restrict__ w3,
    short* __restrict__ out) {
  int i = blockIdx.x * 256 + threadIdx.x;
  if (i >= W_TOTAL) return;
  float v;
  if (i < OFF_WHH0)      v = w0[i - OFF_WIH0];
  else if (i < OFF_WIH1) v = w1[i - OFF_WHH0];
  else if (i < OFF_WHH1) v = w2[i - OFF_WIH1];
  else                   v = w3[i - OFF_WHH1];
  out[i] = f2bf(v);
}

__global__ __launch_bounds__(256) void cvt_x(const float* __restrict__ x,
                                             short* __restrict__ xb) {
  size_t i = ((size_t)blockIdx.x * 256 + threadIdx.x) * 8;
  if (i >= XB_ELEMS) return;
#pragma unroll
  for (int k = 0; k < 8; ++k) xb[i + k] = f2bf(x[i + k]);
}

// Atomic (sc1) zeroing of counters -> no plain-store/sc1-load visibility edge.
__global__ __launch_bounds__(256) void init_cnt(unsigned* __restrict__ c) {
  int i = blockIdx.x * 256 + threadIdx.x;
  if (i < 1024) st32(c + i, 0u);
}

// 256 blocks = (bt = blk&15, ht = blk>>4), 128 thr = 2 waves.
// w0 = GRU layer 0, w1 = layer 1; each owns cols [ht*16,+16), all 3 gates,
// weights VGPR-resident. h exchanged as packed bf16 pairs via sc1 atomics.
// Sync: per-(bt,wave-class) counter; inc after publish + s_waitcnt(0) drain
// (proven R4 recipe). Phase p: w0 computes h1[p], w1 computes h2[p-1].
// Phases 0/1 never read h buffers (h[-1]=0 via skipped hh-MFMAs) -> no h init.
__global__ __launch_bounds__(128, 1) void gru_cnt(
    const short* __restrict__ xb, const short* __restrict__ wb,
    const float* __restrict__ bih0, const float* __restrict__ bhh0,
    const float* __restrict__ bih1, const float* __restrict__ bhh1,
    const float* __restrict__ Wfc, const float* __restrict__ bfc,
    unsigned* __restrict__ h1g, unsigned* __restrict__ h2g,
    unsigned* __restrict__ cnt, float* __restrict__ out) {
  const int tid = threadIdx.x;
  const int lane = tid & 63;
  const int w = tid >> 6;
  const int quad = lane >> 4;
  const int col = lane & 15;
  const int bt = blockIdx.x & 15;   // stride-16 grouping: same bt -> same XCD
  const int ht = blockIdx.x >> 4;
  const int jc = ht * 16 + col;

  __shared__ __align__(16) short sA[2][2][16][LDW];  // [parity][0=h1prev,1=h2prev]

  unsigned* c0 = cnt + bt * 32;        // layer-0 phase counter (16 blocks each inc)
  unsigned* c1 = cnt + 512 + bt * 32;  // layer-1 phase counter

  // staging geometry: lane covers row srow, 64 cols from scol
  const int srow = lane >> 2;
  const int scol = (lane & 3) * 64;
  const int gq = (bt * 16 + srow) * (HH / 4) + (lane & 3) * 16;  // u64 idx

  float hm[4] = {0.f, 0.f, 0.f, 0.f};

  if (w == 0) {
    short8 wI[3][4], wH[3][8];
#pragma unroll
    for (int g = 0; g < 3; ++g) {
#pragma unroll
      for (int f = 0; f < 4; ++f)
        wI[g][f] = *(const short8*)(wb + OFF_WIH0 + (g * HH + jc) * II + f * 32 + quad * 8);
#pragma unroll
      for (int f = 0; f < 8; ++f)
        wH[g][f] = *(const short8*)(wb + OFF_WHH0 + (g * HH + jc) * HH + f * 32 + quad * 8);
    }
    const float bR = bih0[jc] + bhh0[jc];
    const float bZ = bih0[HH + jc] + bhh0[HH + jc];
    const float bNI = bih0[2 * HH + jc];
    const float bNH = bhh0[2 * HH + jc];

#pragma unroll 1
    for (int p = 0; p <= TT; ++p) {
      const int par = p & 1;
      // x[p] fragments first (overlap the spin)
      short8 ax[4];
      if (p < TT) {
        const short* xr = xb + ((size_t)p * BB + bt * 16 + col) * II + quad * 8;
#pragma unroll
        for (int f = 0; f < 4; ++f) ax[f] = *(const short8*)(xr + f * 32);
      }
      if (p > 0) {
        if (lane == 0) spin_ge(c0, 16u * (unsigned)p);
        // stage h1[p-1] (parity (p-1)&1) into sA[par][0]
        const u64* src = (const u64*)(h1g + (size_t)((p + 1) & 1) * (BB * HH / 2)) + gq;
        u64 v[16];
#pragma unroll
        for (int k = 0; k < 16; ++k) v[k] = ld64(src + k);
        u64* d = (u64*)&sA[par][0][srow][scol];
#pragma unroll
        for (int k = 0; k < 16; ++k) d[k] = v[k];
      }
      __syncthreads();

      if (p < TT) {
        floatx4 aR = floatx4{bR, bR, bR, bR};
        floatx4 aZ = floatx4{bZ, bZ, bZ, bZ};
        floatx4 aNI = floatx4{bNI, bNI, bNI, bNI};
        floatx4 aNH = floatx4{bNH, bNH, bNH, bNH};
#pragma unroll
        for (int f = 0; f < 4; ++f) {
          aR = __builtin_amdgcn_mfma_f32_16x16x32_bf16(ax[f], wI[0][f], aR, 0, 0, 0);
          aZ = __builtin_amdgcn_mfma_f32_16x16x32_bf16(ax[f], wI[1][f], aZ, 0, 0, 0);
          aNI = __builtin_amdgcn_mfma_f32_16x16x32_bf16(ax[f], wI[2][f], aNI, 0, 0, 0);
        }
        if (p > 0) {  // p==0: h=0, hh contribution exactly 0 (biases already in acc)
          const short* hA = &sA[par][0][col][0];
#pragma unroll
          for (int f = 0; f < 8; ++f) {
            short8 a = *(const short8*)(hA + f * 32 + quad * 8);
            aR = __builtin_amdgcn_mfma_f32_16x16x32_bf16(a, wH[0][f], aR, 0, 0, 0);
            aZ = __builtin_amdgcn_mfma_f32_16x16x32_bf16(a, wH[1][f], aZ, 0, 0, 0);
            aNH = __builtin_amdgcn_mfma_f32_16x16x32_bf16(a, wH[2][f], aNH, 0, 0, 0);
          }
        }
        unsigned* dst = h1g + (size_t)par * (BB * HH / 2);
#pragma unroll
        for (int i = 0; i < 4; ++i) {
          float r = fast_sigmoid(aR[i]);
          float z = fast_sigmoid(aZ[i]);
          float n = fast_tanh(aNI[i] + r * aNH[i]);
          float h = n + z * (hm[i] - n);
          hm[i] = h;
          unsigned hv = (unsigned)(unsigned short)f2bf(h);
          unsigned ov = (unsigned)__builtin_amdgcn_ds_swizzle((int)hv, 0x041F);
          if (!(lane & 1))
            st32(dst + (bt * 16 + quad * 4 + i) * (HH / 2) + (jc >> 1),
                 hv | (ov << 16));
        }
      }
      drain_then();
      if (lane == 0)
        __hip_atomic_fetch_add(c0, 1u, __ATOMIC_RELAXED, __HIP_MEMORY_SCOPE_AGENT);
    }

    // ---- FC epilogue: out = h2[511] @ Wfc^T + bfc ----
    if (lane == 0) spin_ge(c1, 16u * (unsigned)(TT + 1));
    {
      const u64* src = (const u64*)(h2g + (size_t)1 * (BB * HH / 2)) + gq;  // parity 1
      u64 v[16];
#pragma unroll
      for (int k = 0; k < 16; ++k) v[k] = ld64(src + k);
      u64* d = (u64*)&sA[0][0][srow][scol];
#pragma unroll
      for (int k = 0; k < 16; ++k) d[k] = v[k];
    }
    __syncthreads();
    float bbv = bfc[jc];
    floatx4 acc = floatx4{bbv, bbv, bbv, bbv};
#pragma unroll
    for (int f = 0; f < 8; ++f) {
      short8 a = *(const short8*)(&sA[0][0][col][0] + f * 32 + quad * 8);
      short8 bw = cvt8(Wfc + jc * HH + f * 32 + quad * 8);
      acc = __builtin_amdgcn_mfma_f32_16x16x32_bf16(a, bw, acc, 0, 0, 0);
    }
#pragma unroll
    for (int i = 0; i < 4; ++i)
      out[(size_t)(bt * 16 + quad * 4 + i) * HH + jc] = acc[i];

  } else {
    short8 wI[3][8], wH[3][8];
#pragma unroll
    for (int g = 0; g < 3; ++g) {
#pragma unroll
      for (int f = 0; f < 8; ++f) {
        wI[g][f] = *(const short8*)(wb + OFF_WIH1 + (g * HH + jc) * HH + f * 32 + quad * 8);
        wH[g][f] = *(const short8*)(wb + OFF_WHH1 + (g * HH + jc) * HH + f * 32 + quad * 8);
      }
    }
    const float bR = bih1[jc] + bhh1[jc];
    const float bZ = bih1[HH + jc] + bhh1[HH + jc];
    const float bNI = bih1[2 * HH + jc];
    const float bNH = bhh1[2 * HH + jc];

#pragma unroll 1
    for (int p = 0; p <= TT; ++p) {
      const int par = p & 1;
      if (p > 0) {
        if (lane == 0) spin_ge(c1, 16u * (unsigned)p);
        if (p > 1) {
          // stage h2[p-2] (parity p&1) into sA[par][1]
          const u64* src = (const u64*)(h2g + (size_t)par * (BB * HH / 2)) + gq;
          u64 v[16];
#pragma unroll
          for (int k = 0; k < 16; ++k) v[k] = ld64(src + k);
          u64* d = (u64*)&sA[par][1][srow][scol];
#pragma unroll
          for (int k = 0; k < 16; ++k) d[k] = v[k];
        }
      }
      __syncthreads();

      if (p > 0) {
        floatx4 aR = floatx4{bR, bR, bR, bR};
        floatx4 aZ = floatx4{bZ, bZ, bZ, bZ};
        floatx4 aNI = floatx4{bNI, bNI, bNI, bNI};
        floatx4 aNH = floatx4{bNH, bNH, bNH, bNH};
        const short* h1A = &sA[par][0][col][0];  // h1[p-1], staged by w0
#pragma unroll
        for (int f = 0; f < 8; ++f) {
          short8 a = *(const short8*)(h1A + f * 32 + quad * 8);
          aR = __builtin_amdgcn_mfma_f32_16x16x32_bf16(a, wI[0][f], aR, 0, 0, 0);
          aZ = __builtin_amdgcn_mfma_f32_16x16x32_bf16(a, wI[1][f], aZ, 0, 0, 0);
          aNI = __builtin_amdgcn_mfma_f32_16x16x32_bf16(a, wI[2][f], aNI, 0, 0, 0);
        }
        if (p > 1) {  // p==1: h2[-1]=0, hh contribution exactly 0
          const short* h2A = &sA[par][1][col][0];
#pragma unroll
          for (int f = 0; f < 8; ++f) {
            short8 a = *(const short8*)(h2A + f * 32 + quad * 8);
            aR = __builtin_amdgcn_mfma_f32_16x16x32_bf16(a, wH[0][f], aR, 0, 0, 0);
            aZ = __builtin_amdgcn_mfma_f32_16x16x32_bf16(a, wH[1][f], aZ, 0, 0, 0);
            aNH = __builtin_amdgcn_mfma_f32_16x16x32_bf16(a, wH[2][f], aNH, 0, 0, 0);
          }
        }
        unsigned* dst = h2g + (size_t)((p + 1) & 1) * (BB * HH / 2);  // parity (p-1)&1
#pragma unroll
        for (int i = 0; i < 4; ++i) {
          float r = fast_sigmoid(aR[i]);
          float z = fast_sigmoid(aZ[i]);
          float n = fast_tanh(aNI[i] + r * aNH[i]);
          float h = n + z * (hm[i] - n);
          hm[i] = h;
          unsigned hv = (unsigned)(unsigned short)f2bf(h);
          unsigned ov = (unsigned)__builtin_amdgcn_ds_swizzle((int)hv, 0x041F);
          if (!(lane & 1))
            st32(dst + (bt * 16 + quad * 4 + i) * (HH / 2) + (jc >> 1),
                 hv | (ov << 16));
        }
      }
      drain_then();
      if (lane == 0)
        __hip_atomic_fetch_add(c1, 1u, __ATOMIC_RELAXED, __HIP_MEMORY_SCOPE_AGENT);
    }
    __syncthreads();  // pair with w0's FC-epilogue barrier
  }
}

extern "C" void kernel_launch(void* const* d_in, const int* in_sizes, int n_in,
                              void* d_out, int out_size, void* d_ws,
                              size_t ws_size, hipStream_t stream) {
  const float* x = (const float*)d_in[0];
  const float* Wih0 = (const float*)d_in[1];
  const float* Whh0 = (const float*)d_in[2];
  const float* bih0 = (const float*)d_in[3];
  const float* bhh0 = (const float*)d_in[4];
  const float* Wih1 = (const float*)d_in[5];
  const float* Whh1 = (const float*)d_in[6];
  const float* bih1 = (const float*)d_in[7];
  const float* bhh1 = (const float*)d_in[8];
  const float* Wfc = (const float*)d_in[9];
  const float* bfc = (const float*)d_in[10];

  unsigned* h1g = (unsigned*)d_ws;
  unsigned* h2g = h1g + HBUF_U32;
  short* wb = (short*)(h2g + HBUF_U32);
  short* xbuf = wb + W_TOTAL;
  unsigned* cnt = (unsigned*)(xbuf + XB_ELEMS);

  cvt_weights<<<(W_TOTAL + 255) / 256, 256, 0, stream>>>(Wih0, Whh0, Wih1, Whh1, wb);
  cvt_x<<<(int)((XB_ELEMS / 8 + 255) / 256), 256, 0, stream>>>(x, xbuf);
  init_cnt<<<4, 256, 0, stream>>>(cnt);
  gru_cnt<<<256, 128, 0, stream>>>(xbuf, wb, bih0, bhh0, bih1, bhh1, Wfc, bfc,
                                   h1g, h2g, cnt, (float*)d_out);
}